// Round 5
// baseline (880.564 us; speedup 1.0000x reference)
//
#include <hip/hip_runtime.h>

// Fused windowed multi-head attention for MI355X (gfx950).
// B=8192 windows, N=49 tokens, C=192, H=6 heads, HD=32.
// Inputs/outputs are FP32 (per reference); mask int32. Interior compute bf16 MFMA.
//
// Structure (v5): 1 block per TWO windows, 12 waves (768 threads).
//   Sub-block w = tid/384 owns window blockIdx.x*2+w with its own LDS region;
//   wave tid/64 maps to (window w, head (tid%384)/64). Per-wave code is
//   identical to v4; barriers sync both halves at the same phase points.
//
// Why: occupancy was pinned at ~17.8% (5.7 waves/CU = one 6-wave workgroup)
// across LDS {89.6, 74.2, 50.7} KB and VGPR {128, 88, 84} -> no classical
// resource explains it; the dispatcher appears to co-schedule only ONE
// workgroup per CU for this shape. v5 forces 12 resident waves by putting
// two windows in one workgroup (2 x 49.4 KB LDS = 98.8 KB < 160 KB).
// (v5 first submission died to an infra "container failed twice" error —
// audited for hangs/OOB, none found; resubmitted with cosmetic cleanup only.)
//
// Per-window phases (per 6-wave half-block, one wave per head):
//   phase 1: stage x fp32 -> bf16 (49x192 -> 64x200 padded) + mask bias in LDS
//   phase 2a: Q,K GEMM (swapped operands mfma(W,X) -> Q^T/K^T C-layout),
//             collapsed immediately to bf16 fragments via quad-shuffle xpose.
//   phase 2b: V GEMM (normal operands), v^T -> per-head swizzled LDS.
//   phase 4: per-column-tile fused { S^T slice = mfma(K,Q); masked softmax
//            (lane-local q-rows, 2 shfl_xor); xpose -> P A-fragment }.
//   phase 5: O = P V (v^T from LDS as B operand)
//   phase 6: O tile (64x192) to LDS, cooperative projection GEMM + bias, store
//
// Weights repacked each call fp32 -> bf16 in B-fragment-contiguous layout:
// wp[(kt*COLS + col)*32 + kk] = w[(kt*32+kk)*COLS + col].

typedef __attribute__((ext_vector_type(8))) short short8;
typedef __attribute__((ext_vector_type(4))) float f32x4;

#define SCALE 0.17677669529663687f   // 32^-0.5

__device__ __forceinline__ unsigned short f2bf(float x) {
    union { float f; unsigned int i; } v; v.f = x;
    return (unsigned short)((v.i + 0x7FFFu + ((v.i >> 16) & 1u)) >> 16);
}

// packed f32x2 -> bf16x2 (RNE), 1 instr
__device__ __forceinline__ unsigned int pkbf(float lo, float hi) {
    unsigned int r;
    asm("v_cvt_pk_bf16_f32 %0, %1, %2" : "=v"(r) : "v"(lo), "v"(hi));
    return r;
}

// XOR-swizzled index into a [R][64]-short buffer (row stride 128B = 8 x 16B slots).
__device__ __forceinline__ int swz64(int row, int col) {
    return row * 64 + ((((col >> 3) ^ (row & 7)) << 3) | (col & 7));
}

// C-layout pair (two 16-row tiles: tlo = dims/k 0..15, thi = 16..31) ->
// A/B MFMA fragment. dst lane (quad,l16) elem e needs src reg r=e&3 from
// lane ((quad&1)*2 + (e>>2))*16 + l16, tile selected by quad>>1.
__device__ __forceinline__ short8 xpose(f32x4 tlo, f32x4 thi, int srcA, bool hi) {
    unsigned int pl0 = pkbf(tlo[0], tlo[1]);
    unsigned int pl1 = pkbf(tlo[2], tlo[3]);
    unsigned int ph0 = pkbf(thi[0], thi[1]);
    unsigned int ph1 = pkbf(thi[2], thi[3]);
    unsigned int a0 = (unsigned int)__shfl((int)pl0, srcA);
    unsigned int b0 = (unsigned int)__shfl((int)ph0, srcA);
    unsigned int a1 = (unsigned int)__shfl((int)pl1, srcA);
    unsigned int b1 = (unsigned int)__shfl((int)ph1, srcA);
    unsigned int a2 = (unsigned int)__shfl((int)pl0, srcA + 16);
    unsigned int b2 = (unsigned int)__shfl((int)ph0, srcA + 16);
    unsigned int a3 = (unsigned int)__shfl((int)pl1, srcA + 16);
    unsigned int b3 = (unsigned int)__shfl((int)ph1, srcA + 16);
    union { short8 s8; unsigned int u[4]; } f;
    f.u[0] = hi ? b0 : a0;
    f.u[1] = hi ? b1 : a1;
    f.u[2] = hi ? b2 : a2;
    f.u[3] = hi ? b3 : a3;
    return f.s8;
}

__global__ void repack_kernel(const float* __restrict__ wqkv,
                              const float* __restrict__ wproj,
                              unsigned short* __restrict__ wq_pack,
                              unsigned short* __restrict__ wp_pack) {
    int idx = blockIdx.x * 256 + threadIdx.x;
    if (idx < 6 * 576 * 32) {
        int kk  = idx & 31;
        int col = (idx >> 5) % 576;
        int kt  = idx / (576 * 32);
        wq_pack[idx] = f2bf(wqkv[(kt * 32 + kk) * 576 + col]);
    } else {
        int j = idx - 6 * 576 * 32;
        if (j < 6 * 192 * 32) {
            int kk  = j & 31;
            int col = (j >> 5) % 192;
            int kt  = j / (192 * 32);
            wp_pack[j] = f2bf(wproj[(kt * 32 + kk) * 192 + col]);
        }
    }
}

__global__ __launch_bounds__(768)
void win_attn_kernel(const float* __restrict__ x,
                     const int* __restrict__ mask,
                     const float* __restrict__ bqkv,
                     const float* __restrict__ bproj,
                     const unsigned short* __restrict__ wq,
                     const unsigned short* __restrict__ wpj,
                     float* __restrict__ out) {
    // Per window w: region[w][0..12800)  x tile 64x200 (phases 1-2),
    //                              later O_all 64x200 (phase 6)
    //               region[w][12800..25088) per-head vt[32][64] swizzled (6x2048)
    // vt is DISJOINT from the x tile -> no barrier between phase 2 and 3-5.
    __shared__ __align__(16) unsigned short region[2][25088];
    __shared__ __align__(16) float mbias[2][64];

    const int tid  = threadIdx.x;
    const int w    = tid / 384;                         // sub-block (0/1)
    const int tw   = tid - w * 384;                     // tid within sub-block
    const int b    = blockIdx.x * 2 + w;
    const int lane = tid & 63;      // == tw & 63 (384 = 6 waves)
    const int h    = tw >> 6;       // wave-within-sub-block == head
    const int quad = lane >> 4;
    const int l16  = lane & 15;

    unsigned short* rg = &region[w][0];
    float*          mb = &mbias[w][0];

    // ---------------- phase 1: stage x (fp32 -> bf16), pad, mask bias -----
    const float* xb = x + (size_t)b * 9408;
    for (int i4 = tw; i4 < 2352; i4 += 384) {   // 9408 elems / 4
        int flat = i4 * 4;
        int n = flat / 192, c = flat % 192;      // 192 % 4 == 0: no row cross
        float4 v = *(const float4*)(const void*)&xb[flat];
        uint2 pk;
        pk.x = pkbf(v.x, v.y);
        pk.y = pkbf(v.z, v.w);
        *(uint2*)(void*)&rg[n * 200 + c] = pk;
    }
    if (tw < 375) {                              // zero rows 49..63 (15*200)
        uint4 z = {0u, 0u, 0u, 0u};
        *(uint4*)(void*)&rg[9800 + tw * 8] = z;
    }
    if (tw < 64)
        mb[tw] = (tw < 49 && mask[b * 49 + tw] != 0) ? 0.0f : -1e30f;
    __syncthreads();

    const int  srcA = ((lane & 16) << 1) | l16;   // ((quad&1)*2)*16 + l16
    const bool hiq  = (lane & 32) != 0;           // quad>>1

    int colb[6];
    #pragma unroll
    for (int t = 0; t < 6; ++t) colb[t] = (t >> 1) * 192 + h * 32 + (t & 1) * 16;

    // ---------------- phase 2a: Q,K GEMM (swapped operands) ---------------
    // acc[t][nt]: lane holds Y[token=nt*16+l16][outcol = colb[t]+quad*4+r]
    short8 qf[4], kf[4];
    {
        f32x4 acc[4][4];
        #pragma unroll
        for (int t = 0; t < 4; ++t)
            #pragma unroll
            for (int mt = 0; mt < 4; ++mt)
                acc[t][mt] = (f32x4){0.f, 0.f, 0.f, 0.f};

        #pragma unroll
        for (int kt = 0; kt < 6; ++kt) {
            short8 af[4];
            #pragma unroll
            for (int mt = 0; mt < 4; ++mt)
                af[mt] = *(const short8*)(const void*)
                         &rg[(mt * 16 + l16) * 200 + kt * 32 + quad * 8];
            #pragma unroll
            for (int t = 0; t < 4; ++t) {
                short8 bw = *(const short8*)(const void*)
                            &wq[(size_t)(kt * 576 + colb[t] + l16) * 32 + quad * 8];
                #pragma unroll
                for (int mt = 0; mt < 4; ++mt)
                    acc[t][mt] = __builtin_amdgcn_mfma_f32_16x16x32_bf16(
                                     bw, af[mt], acc[t][mt], 0, 0, 0);
            }
        }
        // bias: outcol = colb[t] + quad*4 + r
        #pragma unroll
        for (int t = 0; t < 4; ++t) {
            f32x4 bq = *(const f32x4*)(const void*)&bqkv[colb[t] + quad * 4];
            #pragma unroll
            for (int nt = 0; nt < 4; ++nt)
                #pragma unroll
                for (int r = 0; r < 4; ++r)
                    acc[t][nt][r] += bq[r];
        }
        // collapse to bf16 fragments immediately (frees 64 f32 regs)
        #pragma unroll
        for (int nt = 0; nt < 4; ++nt) {
            qf[nt] = xpose(acc[0][nt], acc[1][nt], srcA, hiq);
            kf[nt] = xpose(acc[2][nt], acc[3][nt], srcA, hiq);
        }
    }

    // ---------------- phase 2b: V GEMM (normal operands) + vt -> LDS ------
    unsigned short* vtb = &rg[12800 + h * 2048];   // vt[32][64] swizzled
    {
        f32x4 accv[2][4];
        #pragma unroll
        for (int t = 0; t < 2; ++t)
            #pragma unroll
            for (int mt = 0; mt < 4; ++mt)
                accv[t][mt] = (f32x4){0.f, 0.f, 0.f, 0.f};

        #pragma unroll
        for (int kt = 0; kt < 6; ++kt) {
            short8 af[4];
            #pragma unroll
            for (int mt = 0; mt < 4; ++mt)
                af[mt] = *(const short8*)(const void*)
                         &rg[(mt * 16 + l16) * 200 + kt * 32 + quad * 8];
            #pragma unroll
            for (int t = 0; t < 2; ++t) {
                short8 bw = *(const short8*)(const void*)
                            &wq[(size_t)(kt * 576 + colb[4 + t] + l16) * 32 + quad * 8];
                #pragma unroll
                for (int mt = 0; mt < 4; ++mt)
                    accv[t][mt] = __builtin_amdgcn_mfma_f32_16x16x32_bf16(
                                      af[mt], bw, accv[t][mt], 0, 0, 0);
            }
        }
        // bias (outcol = colb[4+t]+l16) and store v^T (swizzled)
        #pragma unroll
        for (int t = 0; t < 2; ++t) {
            float bv = bqkv[colb[4 + t] + l16];
            #pragma unroll
            for (int mt = 0; mt < 4; ++mt) {
                int d = t * 16 + l16;
                uint2 pk;
                pk.x = pkbf(accv[t][mt][0] + bv, accv[t][mt][1] + bv);
                pk.y = pkbf(accv[t][mt][2] + bv, accv[t][mt][3] + bv);
                *(uint2*)(void*)&vtb[swz64(d, mt * 16 + quad * 4)] = pk;
            }
        }
    }
    // NO barrier: vt region disjoint from x tile; phases 4-5 are wave-local.

    // ---------------- phase 4: per-slice S^T + masked softmax + P-frag ----
    f32x4 mb4[4];
    #pragma unroll
    for (int mt = 0; mt < 4; ++mt)
        mb4[mt] = *(const f32x4*)(const void*)&mb[mt * 16 + quad * 4];

    short8 ap[4][2];
    #pragma unroll
    for (int nt = 0; nt < 4; ++nt) {
        // sr[mt]: lane holds S[q=nt*16+l16][k=mt*16+quad*4+r]
        f32x4 sr[4];
        #pragma unroll
        for (int mt = 0; mt < 4; ++mt) {
            sr[mt] = (f32x4){0.f, 0.f, 0.f, 0.f};
            sr[mt] = __builtin_amdgcn_mfma_f32_16x16x32_bf16(
                         kf[mt], qf[nt], sr[mt], 0, 0, 0);
        }
        float pm[4];
        #pragma unroll
        for (int mt = 0; mt < 4; ++mt) {
            #pragma unroll
            for (int r = 0; r < 4; ++r)
                sr[mt][r] = sr[mt][r] * SCALE + mb4[mt][r];
            pm[mt] = fmaxf(fmaxf(sr[mt][0], sr[mt][1]),
                           fmaxf(sr[mt][2], sr[mt][3]));
        }
        float mx = fmaxf(fmaxf(pm[0], pm[1]), fmaxf(pm[2], pm[3]));
        mx = fmaxf(mx, __shfl_xor(mx, 16));
        mx = fmaxf(mx, __shfl_xor(mx, 32));
        float ps[4];
        #pragma unroll
        for (int mt = 0; mt < 4; ++mt) {
            #pragma unroll
            for (int r = 0; r < 4; ++r)
                sr[mt][r] = __expf(sr[mt][r] - mx);
            ps[mt] = (sr[mt][0] + sr[mt][1]) + (sr[mt][2] + sr[mt][3]);
        }
        float sum = (ps[0] + ps[1]) + (ps[2] + ps[3]);
        sum += __shfl_xor(sum, 16);
        sum += __shfl_xor(sum, 32);
        float inv = 1.0f / sum;
        #pragma unroll
        for (int mt = 0; mt < 4; ++mt)
            #pragma unroll
            for (int r = 0; r < 4; ++r)
                sr[mt][r] *= inv;
        // P^T slice -> A-fragments (no LDS round-trip)
        ap[nt][0] = xpose(sr[0], sr[1], srcA, hiq);
        ap[nt][1] = xpose(sr[2], sr[3], srcA, hiq);
    }

    // ---------------- phase 5: O = P V -----------------------------------
    f32x4 o[4][2];
    #pragma unroll
    for (int mo = 0; mo < 4; ++mo)
        #pragma unroll
        for (int dt = 0; dt < 2; ++dt)
            o[mo][dt] = (f32x4){0.f, 0.f, 0.f, 0.f};

    #pragma unroll
    for (int kt = 0; kt < 2; ++kt) {
        short8 bvv[2];
        #pragma unroll
        for (int dt = 0; dt < 2; ++dt)
            bvv[dt] = *(const short8*)(const void*)
                      &vtb[swz64(dt * 16 + l16, kt * 32 + quad * 8)];
        #pragma unroll
        for (int mo = 0; mo < 4; ++mo)
            #pragma unroll
            for (int dt = 0; dt < 2; ++dt)
                o[mo][dt] = __builtin_amdgcn_mfma_f32_16x16x32_bf16(
                                ap[mo][kt], bvv[dt], o[mo][dt], 0, 0, 0);
    }

    __syncthreads();   // all waves past phase-2 x reads; rg[0..] becomes O_all
    #pragma unroll
    for (int dt = 0; dt < 2; ++dt)
        #pragma unroll
        for (int mt = 0; mt < 4; ++mt)
            #pragma unroll
            for (int r = 0; r < 4; ++r)
                rg[(mt * 16 + quad * 4 + r) * 200 + h * 32 + dt * 16 + l16]
                    = f2bf(o[mt][dt][r]);
    __syncthreads();

    // ---------------- phase 6: projection GEMM + bias + fp32 store -------
    f32x4 po[2][4];
    #pragma unroll
    for (int nt = 0; nt < 2; ++nt)
        #pragma unroll
        for (int mt = 0; mt < 4; ++mt)
            po[nt][mt] = (f32x4){0.f, 0.f, 0.f, 0.f};

    #pragma unroll
    for (int kt = 0; kt < 6; ++kt) {
        short8 ao[4];
        #pragma unroll
        for (int mt = 0; mt < 4; ++mt)
            ao[mt] = *(const short8*)(const void*)
                     &rg[(mt * 16 + l16) * 200 + kt * 32 + quad * 8];
        #pragma unroll
        for (int nt = 0; nt < 2; ++nt) {
            int col = h * 32 + nt * 16 + l16;
            short8 bw = *(const short8*)(const void*)
                        &wpj[(size_t)(kt * 192 + col) * 32 + quad * 8];
            #pragma unroll
            for (int mt = 0; mt < 4; ++mt)
                po[nt][mt] = __builtin_amdgcn_mfma_f32_16x16x32_bf16(
                                 ao[mt], bw, po[nt][mt], 0, 0, 0);
        }
    }

    #pragma unroll
    for (int nt = 0; nt < 2; ++nt) {
        int col = h * 32 + nt * 16 + l16;
        float bv = bproj[col];
        #pragma unroll
        for (int mt = 0; mt < 4; ++mt)
            #pragma unroll
            for (int r = 0; r < 4; ++r) {
                int row = mt * 16 + quad * 4 + r;
                if (row < 49)
                    out[(size_t)b * 9408 + row * 192 + col] = po[nt][mt][r] + bv;
            }
    }
}

extern "C" void kernel_launch(void* const* d_in, const int* in_sizes, int n_in,
                              void* d_out, int out_size, void* d_ws, size_t ws_size,
                              hipStream_t stream) {
    const float* x      = (const float*)d_in[0];
    const int*   mask   = (const int*)d_in[1];
    const float* w_qkv  = (const float*)d_in[2];
    const float* b_qkv  = (const float*)d_in[3];
    const float* w_proj = (const float*)d_in[4];
    const float* b_proj = (const float*)d_in[5];
    float*       out    = (float*)d_out;

    unsigned short* wq_pack = (unsigned short*)d_ws;          // 110592 elems
    unsigned short* wp_pack = wq_pack + 110592;               //  36864 elems

    repack_kernel<<<(110592 + 36864 + 255) / 256, 256, 0, stream>>>(
        w_qkv, w_proj, wq_pack, wp_pack);
    win_attn_kernel<<<4096, 768, 0, stream>>>(x, mask, b_qkv, b_proj,
                                              wq_pack, wp_pack, out);
}